// Round 8
// baseline (177.356 us; speedup 1.0000x reference)
//
#include <hip/hip_runtime.h>
#include <cmath>

// RetinaNet focal + smooth-L1 loss. R12 restructure.
//
// R7-R11 post-mortem: effective HBM fetch rate pinned at ~750-850 GB/s
// across FOUR different pipelines (predicated ring / serial ring /
// batched / global_load_lds DMA; occupancy 22-55%, VGPR 32-68). The rate,
// not the time, is the invariant -> per-wave ILP was never the lever.
// All versions were TLP-starved (grid- or LDS-limited, barrier lockstep).
// The only measured 6.3 TB/s pattern on this chip (m13 copy) is: no LDS
// staging, no barriers, grid-stride, 32 waves/CU.
// R12: split. Kernel A (assignment) writes label+1 as u8 map (307 KB in
// workspace, L2-resident) + reg/pos atomics. Kernel B (focal) is a pure
// m13-shaped streaming reduction over the 98 MB cls stream: 2048 blocks,
// lean body (int label compares, no staging, no barriers until the final
// block reduce), VGPR<=64 -> 32 waves/CU. Kernel-boundary coherence
// makes A's labels visible to B (proven faster than in-kernel fencing).
#define GT_CAP 64

typedef float fvec4 __attribute__((ext_vector_type(4)));

// ---------------- Kernel A: per-anchor assignment ----------------
__global__ __launch_bounds__(256) void retina_assign(
    const float* __restrict__ reg_heads,   // (B, N, 4)
    const float* __restrict__ anchors,     // (B, N, 4) — identical across B
    const float* __restrict__ annots,      // (B, M, 5)
    float* __restrict__ ws,                // [B] cls, [B] reg, [B] pos
    unsigned char* __restrict__ lab8,      // (B, N): label+1 (0=ignore, 1=bg, c+2=pos c)
    int N, int M, int B)
{
    const int b = blockIdx.y;
    const int n = (blockIdx.x << 8) + threadIdx.x;
    const int t = threadIdx.x;

    __shared__ float s_ann[5 * GT_CAP];
    __shared__ float s_red[8];

    const int mm = (M > GT_CAP) ? GT_CAP : M;
    for (int i = t; i < 5 * mm; i += 256)
        s_ann[i] = annots[(size_t)b * 5 * M + i];
    __syncthreads();

    float reg_acc = 0.0f;
    float pos_cnt = 0.0f;
    float label   = -1.0f;
    if (n < N) {
        // anchors identical across batch: read plane 0 (cache-served for b>0)
        const float4 a = *(const float4*)(anchors + (size_t)n * 4);
        const bool inside = (a.x > 0.0f) && (a.y > 0.0f) &&
                            (a.z < 640.0f) && (a.w < 640.0f);
        if (inside) {
            const float area_a = (a.z - a.x) * (a.w - a.y);
            float best = -3.0e38f;
            int   bi   = 0;
            bool  any  = false;
            for (int m = 0; m < mm; ++m) {
                const float gx1 = s_ann[m*5+0], gy1 = s_ann[m*5+1];
                const float gx2 = s_ann[m*5+2], gy2 = s_ann[m*5+3];
                const float gc  = s_ann[m*5+4];
                float v = -1.0f;
                if (gc >= 0.0f) {
                    any = true;
                    const float iw = fmaxf(fminf(a.z, gx2) - fmaxf(a.x, gx1), 0.0f);
                    const float ih = fmaxf(fminf(a.w, gy2) - fmaxf(a.y, gy1), 0.0f);
                    const float inter = iw * ih;
                    v = inter / (area_a + (gx2 - gx1) * (gy2 - gy1) - inter);
                }
                if (v > best) { best = v; bi = m; }   // first-max == jnp.argmax
            }
            if (any) {
                if (best < 0.4f)      label = 0.0f;
                else if (best > 0.5f) label = s_ann[bi*5+4] + 1.0f;
            }
            if (label > 0.0f) {
                pos_cnt = 1.0f;
                const float aw = a.z - a.x, ah = a.w - a.y;
                const float acx = a.x + 0.5f * aw, acy = a.y + 0.5f * ah;
                const float gw = fmaxf(s_ann[bi*5+2] - s_ann[bi*5+0], 1.0f);
                const float gh = fmaxf(s_ann[bi*5+3] - s_ann[bi*5+1], 1.0f);
                const float gcx = s_ann[bi*5+0] + 0.5f * gw;
                const float gcy = s_ann[bi*5+1] + 0.5f * gh;
                const float tx = (gcx - acx) / aw * 10.0f;
                const float ty = (gcy - acy) / ah * 10.0f;
                const float tw = __logf(gw / aw) * 5.0f;
                const float th = __logf(gh / ah) * 5.0f;
                const float4 r = *(const float4*)(reg_heads + ((size_t)b * N + n) * 4);
                const float dx[4] = { fabsf(r.x - tx), fabsf(r.y - ty),
                                      fabsf(r.z - tw), fabsf(r.w - th) };
                #pragma unroll
                for (int j = 0; j < 4; ++j) {
                    const float x = dx[j];
                    reg_acc += (x < (1.0f / 9.0f)) ? 4.5f * x * x
                                                   : x - (1.0f / 18.0f);
                }
            }
        }
        lab8[(size_t)b * N + n] = (unsigned char)(label + 1.0f);
    }

    // block reduction (reg, pos)
    const int lane = t & 63, wid = t >> 6;
    #pragma unroll
    for (int off = 32; off > 0; off >>= 1) {
        reg_acc += __shfl_down(reg_acc, off, 64);
        pos_cnt += __shfl_down(pos_cnt, off, 64);
    }
    if (lane == 0) { s_red[wid] = reg_acc; s_red[4 + wid] = pos_cnt; }
    __syncthreads();
    if (t == 0) {
        const float r = s_red[0] + s_red[1] + s_red[2] + s_red[3];
        const float p = s_red[4] + s_red[5] + s_red[6] + s_red[7];
        if (r != 0.0f) atomicAdd(&ws[B + b], r);
        if (p != 0.0f) atomicAdd(&ws[2 * B + b], p);
    }
}

// ---------------- Kernel B: focal-loss streaming reduction ----------------
// lab8 value lv: 0 = ignore, 1 = background, c+2 = positive class c.
// mask = lv>=1; is_pos for quad c4, slot j  <=>  lv == 4*c4 + 2 + j.
__device__ __forceinline__ float quad_loss(const float* __restrict__ plane,
                                           const unsigned char* __restrict__ labp,
                                           unsigned q)
{
    const unsigned a  = q / 20u;
    const unsigned c4 = q - a * 20u;
    const int   lv = (int)labp[a];
    const fvec4 v  = *(const fvec4*)(plane + 4u * (size_t)q);
    const int   cb = (int)(c4 * 4u) + 2;
    float local = 0.0f;
    #pragma unroll
    for (int j = 0; j < 4; ++j) {
        const float p      = fminf(fmaxf(v[j], 1.0e-4f), 1.0f - 1.0e-4f);
        const bool  is_pos = (lv == cb + j);
        const float pt     = is_pos ? p : 1.0f - p;
        const float alpha  = is_pos ? 0.25f : 0.75f;
        const float om     = 1.0f - pt;
        local += alpha * om * om * (-__logf(pt));
    }
    return (lv >= 1) ? local : 0.0f;
}

__global__ __launch_bounds__(256) void retina_focal(
    const float* __restrict__ cls_heads,   // (B, N, 80)
    const unsigned char* __restrict__ lab8,
    float* __restrict__ ws,
    int N)
{
    const int b = blockIdx.y;
    const int t = threadIdx.x;
    const unsigned TOTP   = (unsigned)N * 20u;        // quads per image
    const unsigned STRIDE = gridDim.x << 8;           // threads per image

    const float*         plane = cls_heads + (size_t)b * (size_t)N * 80;
    const unsigned char* labp  = lab8 + (size_t)b * (size_t)N;

    __shared__ float s_red[4];

    float acc = 0.0f;
    unsigned q = (blockIdx.x << 8) + (unsigned)t;
    for (; q + STRIDE < TOTP; q += 2u * STRIDE) {
        acc += quad_loss(plane, labp, q);
        acc += quad_loss(plane, labp, q + STRIDE);
    }
    if (q < TOTP) acc += quad_loss(plane, labp, q);

    const int lane = t & 63, wid = t >> 6;
    #pragma unroll
    for (int off = 32; off > 0; off >>= 1)
        acc += __shfl_down(acc, off, 64);
    if (lane == 0) s_red[wid] = acc;
    __syncthreads();
    if (t == 0) {
        const float c = s_red[0] + s_red[1] + s_red[2] + s_red[3];
        if (c != 0.0f) atomicAdd(&ws[b], c);
    }
}

// ---------------- finalize ----------------
__global__ void retina_final(const float* __restrict__ ws,
                             float* __restrict__ out, int B)
{
    if (threadIdx.x == 0 && blockIdx.x == 0) {
        float cl = 0.0f, rl = 0.0f, nv = 0.0f;
        for (int b = 0; b < B; ++b) {
            const float pos = ws[2 * B + b];
            if (pos > 0.0f) {
                cl += ws[b]     / fmaxf(pos, 1.0f);
                rl += ws[B + b] / fmaxf(4.0f * pos, 1.0f);
                nv += 1.0f;
            }
        }
        const float n = fmaxf(nv, 1.0f);
        out[0] = cl / n;
        out[1] = rl / n;
    }
}

extern "C" void kernel_launch(void* const* d_in, const int* in_sizes, int n_in,
                              void* d_out, int out_size, void* d_ws, size_t ws_size,
                              hipStream_t stream) {
    const float* cls = (const float*)d_in[0];
    const float* reg = (const float*)d_in[1];
    const float* anc = (const float*)d_in[2];
    const float* ann = (const float*)d_in[3];

    const int B = 4;
    const int N = in_sizes[1] / (4 * B);      // 76725
    const int M = in_sizes[3] / (5 * B);      // 16
    float* ws = (float*)d_ws;
    // label map lives in workspace after the 12 accumulators (~307 KB total)
    unsigned char* lab8 = (unsigned char*)d_ws + 48;

    (void)hipMemsetAsync(d_ws, 0, 12 * sizeof(float), stream);

    dim3 gridA((N + 255) / 256, B);           // 300 x 4
    retina_assign<<<gridA, 256, 0, stream>>>(reg, anc, ann, ws, lab8, N, M, B);

    dim3 gridB(512, B);                       // 2048 blocks -> 32 waves/CU
    retina_focal<<<gridB, 256, 0, stream>>>(cls, lab8, ws, N);

    retina_final<<<1, 64, 0, stream>>>(ws, (float*)d_out, B);
}

// Round 9
// 167.752 us; speedup vs baseline: 1.0572x; 1.0572x over previous
//
#include <hip/hip_runtime.h>
#include <cmath>

// RetinaNet focal + smooth-L1 loss. Fused main + finalize (R0 structure —
// best measured: 162.8us total, main ~42us). B=4, C=80 fixed.
//
// R8-R12 post-mortem (six structures): effective cls read rate pins at
// ~1.7 TB/s regardless of structure — predicated ring / serial ring /
// batched VGPR / global_load_lds DMA / z-split / pure 32-wave-CU
// streaming (R12) all land 52-58us for the ~98MB stream. R4 steady-state
// (FETCH=48KB, fully L3-served) ALSO took 58us -> the cap is the
// load path (L2 fill / miss handling), not HBM, TLP, MLP, or VALU
// (31-37% busy throughout). ~114us/iter is untouchable harness poison
// fill. Only remaining levers: bytes (R0's predication skips ~35%) and
// the path itself.
// R13: single-variable test on the R0 base — __builtin_nontemporal_load
// (MUBUF nt/sc hints) on the two cls load sites. If the cap is
// L2-allocation, NT streams faster; if neutral, R0 is the floor.
#define GT_CAP 64
#define PF 4                 // software-pipeline depth (outstanding loads/wave)

typedef float fvec4 __attribute__((ext_vector_type(4)));

__global__ __launch_bounds__(256) void retina_main(
    const float* __restrict__ cls_heads,   // (B, N, 80)
    const float* __restrict__ reg_heads,   // (B, N, 4)
    const float* __restrict__ anchors,     // (B, N, 4) — broadcast across B
    const float* __restrict__ annots,      // (B, M, 5)
    float* __restrict__ ws,                // [B] cls, [B] reg, [B] pos
    int N, int M, int B)
{
    const int b  = blockIdx.y;
    const int n0 = blockIdx.x << 8;
    const int t  = threadIdx.x;

    __shared__ float s_ann[5 * GT_CAP];
    __shared__ float s_lab[256];
    __shared__ float s_red[12];

    const int mm = (M > GT_CAP) ? GT_CAP : M;
    for (int i = t; i < 5 * mm; i += 256)
        s_ann[i] = annots[(size_t)b * 5 * M + i];
    __syncthreads();

    // ---- phase 1: per-anchor assignment ----
    float reg_acc = 0.0f;
    float pos_cnt = 0.0f;
    float label   = -1.0f;
    const int n = n0 + t;
    if (n < N) {
        // anchors identical across batch: read plane 0 (cache-served for b>0)
        const float4 a = *(const float4*)(anchors + (size_t)n * 4);
        const bool inside = (a.x > 0.0f) && (a.y > 0.0f) &&
                            (a.z < 640.0f) && (a.w < 640.0f);
        if (inside) {
            const float area_a = (a.z - a.x) * (a.w - a.y);
            float best = -3.0e38f;
            int   bi   = 0;
            bool  any  = false;
            for (int m = 0; m < mm; ++m) {
                const float gx1 = s_ann[m*5+0], gy1 = s_ann[m*5+1];
                const float gx2 = s_ann[m*5+2], gy2 = s_ann[m*5+3];
                const float gc  = s_ann[m*5+4];
                float v = -1.0f;
                if (gc >= 0.0f) {
                    any = true;
                    const float iw = fmaxf(fminf(a.z, gx2) - fmaxf(a.x, gx1), 0.0f);
                    const float ih = fmaxf(fminf(a.w, gy2) - fmaxf(a.y, gy1), 0.0f);
                    const float inter = iw * ih;
                    v = inter / (area_a + (gx2 - gx1) * (gy2 - gy1) - inter);
                }
                if (v > best) { best = v; bi = m; }   // first-max == jnp.argmax
            }
            if (any) {
                if (best < 0.4f)      label = 0.0f;
                else if (best > 0.5f) label = s_ann[bi*5+4] + 1.0f;
            }
            if (label > 0.0f) {
                pos_cnt = 1.0f;
                const float aw = a.z - a.x, ah = a.w - a.y;
                const float acx = a.x + 0.5f * aw, acy = a.y + 0.5f * ah;
                const float gw = fmaxf(s_ann[bi*5+2] - s_ann[bi*5+0], 1.0f);
                const float gh = fmaxf(s_ann[bi*5+3] - s_ann[bi*5+1], 1.0f);
                const float gcx = s_ann[bi*5+0] + 0.5f * gw;
                const float gcy = s_ann[bi*5+1] + 0.5f * gh;
                const float tx = (gcx - acx) / aw * 10.0f;
                const float ty = (gcy - acy) / ah * 10.0f;
                const float tw = __logf(gw / aw) * 5.0f;
                const float th = __logf(gh / ah) * 5.0f;
                const float4 r = *(const float4*)(reg_heads + ((size_t)b * N + n) * 4);
                const float dx[4] = { fabsf(r.x - tx), fabsf(r.y - ty),
                                      fabsf(r.z - tw), fabsf(r.w - th) };
                #pragma unroll
                for (int j = 0; j < 4; ++j) {
                    const float x = dx[j];
                    reg_acc += (x < (1.0f / 9.0f)) ? 4.5f * x * x
                                                   : x - (1.0f / 18.0f);
                }
            }
        }
    }
    s_lab[t] = label;
    const int anyValid = __syncthreads_or(label >= 0.0f ? 1 : 0);

    // ---- phase 2: focal loss, software-pipelined depth-PF conditional loads ----
    // Loads stay exec-mask-conditional (lab<0 lanes issue nothing — the ~35%
    // byte skip is the one lever proven to beat the 1.7 TB/s path cap).
    // R13: loads are NONTEMPORAL (nt) — single-variable change vs R0.
    float cls_acc = 0.0f;
    if (anyValid) {
        const float* cls_base = cls_heads + ((size_t)b * N + n0) * 80;
        int ap = t / 20, c4p = t - (t / 20) * 20;   // prefetch iterator
        int c4c = c4p;                        // process iterator (chunk only)
        float labb[PF];
        fvec4 pb[PF];
        #pragma unroll
        for (int k = 0; k < PF; ++k) {
            const float lab = s_lab[ap];
            fvec4 v = {0.5f, 0.5f, 0.5f, 0.5f};
            if (lab >= 0.0f)
                v = __builtin_nontemporal_load(
                        (const fvec4*)(cls_base + 4 * t + 1024 * k));
            labb[k] = lab; pb[k] = v;
            ap += 12; c4p += 16; if (c4p >= 20) { c4p -= 20; ++ap; }
        }
        #pragma unroll
        for (int k = 0; k < 20; ++k) {
            const float lab = labb[k % PF];
            const fvec4 v   = pb[k % PF];
            if (k + PF < 20) {                 // refill slot with iter k+PF
                const float labn = s_lab[ap];
                fvec4 vn = {0.5f, 0.5f, 0.5f, 0.5f};
                if (labn >= 0.0f)
                    vn = __builtin_nontemporal_load(
                            (const fvec4*)(cls_base + 4 * t + 1024 * (k + PF)));
                labb[k % PF] = labn; pb[k % PF] = vn;
                ap += 12; c4p += 16; if (c4p >= 20) { c4p -= 20; ++ap; }
            }
            const float mask = (lab >= 0.0f) ? 1.0f : 0.0f;
            const float pv[4] = { v.x, v.y, v.z, v.w };
            const float cb = (float)(c4c * 4 + 1);
            float local = 0.0f;
            #pragma unroll
            for (int j = 0; j < 4; ++j) {
                const float p = fminf(fmaxf(pv[j], 1.0e-4f), 1.0f - 1.0e-4f);
                const bool  is_pos = (lab == cb + (float)j);
                const float pt     = is_pos ? p : 1.0f - p;
                const float alpha  = is_pos ? 0.25f : 0.75f;
                const float om     = 1.0f - pt;
                local += alpha * om * om * (-__logf(pt));
            }
            cls_acc += mask * local;
            c4c += 16; if (c4c >= 20) c4c -= 20;
        }
    }

    // ---- block reduction ----
    const int lane = t & 63, wid = t >> 6;
    #pragma unroll
    for (int off = 32; off > 0; off >>= 1) {
        cls_acc += __shfl_down(cls_acc, off, 64);
        reg_acc += __shfl_down(reg_acc, off, 64);
        pos_cnt += __shfl_down(pos_cnt, off, 64);
    }
    if (lane == 0) {
        s_red[wid]     = cls_acc;
        s_red[4 + wid] = reg_acc;
        s_red[8 + wid] = pos_cnt;
    }
    __syncthreads();
    if (t == 0) {
        const float c = s_red[0] + s_red[1] + s_red[2]  + s_red[3];
        const float r = s_red[4] + s_red[5] + s_red[6]  + s_red[7];
        const float p = s_red[8] + s_red[9] + s_red[10] + s_red[11];
        if (c != 0.0f) atomicAdd(&ws[b], c);
        if (r != 0.0f) atomicAdd(&ws[B + b], r);
        if (p != 0.0f) atomicAdd(&ws[2 * B + b], p);
    }
}

__global__ void retina_final(const float* __restrict__ ws,
                             float* __restrict__ out, int B)
{
    if (threadIdx.x == 0 && blockIdx.x == 0) {
        float cl = 0.0f, rl = 0.0f, nv = 0.0f;
        for (int b = 0; b < B; ++b) {
            const float pos = ws[2 * B + b];
            if (pos > 0.0f) {
                cl += ws[b]     / fmaxf(pos, 1.0f);
                rl += ws[B + b] / fmaxf(4.0f * pos, 1.0f);
                nv += 1.0f;
            }
        }
        const float n = fmaxf(nv, 1.0f);
        out[0] = cl / n;
        out[1] = rl / n;
    }
}

extern "C" void kernel_launch(void* const* d_in, const int* in_sizes, int n_in,
                              void* d_out, int out_size, void* d_ws, size_t ws_size,
                              hipStream_t stream) {
    const float* cls = (const float*)d_in[0];
    const float* reg = (const float*)d_in[1];
    const float* anc = (const float*)d_in[2];
    const float* ann = (const float*)d_in[3];

    const int B = 4;
    const int N = in_sizes[1] / (4 * B);      // 76725
    const int M = in_sizes[3] / (5 * B);      // 16
    float* ws = (float*)d_ws;

    (void)hipMemsetAsync(d_ws, 0, 12 * sizeof(float), stream);

    dim3 grid((N + 255) / 256, B);
    retina_main<<<grid, 256, 0, stream>>>(cls, reg, anc, ann, ws, N, M, B);
    retina_final<<<1, 64, 0, stream>>>(ws, (float*)d_out, B);
}

// Round 10
// 163.960 us; speedup vs baseline: 1.0817x; 1.0231x over previous
//
#include <hip/hip_runtime.h>
#include <cmath>

// RetinaNet focal + smooth-L1 loss. Split structure (main + finalize):
// in-kernel device fences/atomic-counter finalize measured +25-30us vs
// kernel-boundary coherence. B=4, C=80 fixed.
//
// ===== Session conclusion (R0-R13) =====
// Best measured: THIS kernel (R0 structure), 162.8us total, main ~40-42us.
// Six alternative structures (predicated ring / serial ring / batched
// VGPR pb[20] / global_load_lds DMA / z-split / pure 32-wave-CU grid-
// stride streaming) + NT loads ALL pin the cls stream at ~0.85 TB/s HBM /
// ~1.7 TB/s delivered, 52-64us. Mechanism (fits all 7 data points):
// WRITEBACK-DRAIN CONTENTION — the harness's 2x393MB poison fills leave
// ~256MB dirty in L3; main runs serially right after and its reads
// contend with that drain for ~35-40us regardless of kernel structure.
// Structural floor: 118us fills (untouchable) + ~40us main-during-drain
// (predication already minimizes demanded bytes; focal loss irreducibly
// needs all 80 logits per non-ignored anchor) + ~5us memset/final
// = ~163us = this kernel's measurement. ILP/TLP/MLP/occupancy knobs are
// all non-levers here (proven R2-R12); NT loads slightly negative (R13).
#define GT_CAP 64
#define PF 4                 // software-pipeline depth (outstanding loads/wave)

typedef float fvec4 __attribute__((ext_vector_type(4)));

__global__ __launch_bounds__(256) void retina_main(
    const float* __restrict__ cls_heads,   // (B, N, 80)
    const float* __restrict__ reg_heads,   // (B, N, 4)
    const float* __restrict__ anchors,     // (B, N, 4) — broadcast across B
    const float* __restrict__ annots,      // (B, M, 5)
    float* __restrict__ ws,                // [B] cls, [B] reg, [B] pos
    int N, int M, int B)
{
    const int b  = blockIdx.y;
    const int n0 = blockIdx.x << 8;
    const int t  = threadIdx.x;

    __shared__ float s_ann[5 * GT_CAP];
    __shared__ float s_lab[256];
    __shared__ float s_red[12];

    const int mm = (M > GT_CAP) ? GT_CAP : M;
    for (int i = t; i < 5 * mm; i += 256)
        s_ann[i] = annots[(size_t)b * 5 * M + i];
    __syncthreads();

    // ---- phase 1: per-anchor assignment ----
    float reg_acc = 0.0f;
    float pos_cnt = 0.0f;
    float label   = -1.0f;
    const int n = n0 + t;
    if (n < N) {
        // anchors identical across batch: read plane 0 (cache-served for b>0)
        const float4 a = *(const float4*)(anchors + (size_t)n * 4);
        const bool inside = (a.x > 0.0f) && (a.y > 0.0f) &&
                            (a.z < 640.0f) && (a.w < 640.0f);
        if (inside) {
            const float area_a = (a.z - a.x) * (a.w - a.y);
            float best = -3.0e38f;
            int   bi   = 0;
            bool  any  = false;
            for (int m = 0; m < mm; ++m) {
                const float gx1 = s_ann[m*5+0], gy1 = s_ann[m*5+1];
                const float gx2 = s_ann[m*5+2], gy2 = s_ann[m*5+3];
                const float gc  = s_ann[m*5+4];
                float v = -1.0f;
                if (gc >= 0.0f) {
                    any = true;
                    const float iw = fmaxf(fminf(a.z, gx2) - fmaxf(a.x, gx1), 0.0f);
                    const float ih = fmaxf(fminf(a.w, gy2) - fmaxf(a.y, gy1), 0.0f);
                    const float inter = iw * ih;
                    v = inter / (area_a + (gx2 - gx1) * (gy2 - gy1) - inter);
                }
                if (v > best) { best = v; bi = m; }   // first-max == jnp.argmax
            }
            if (any) {
                if (best < 0.4f)      label = 0.0f;
                else if (best > 0.5f) label = s_ann[bi*5+4] + 1.0f;
            }
            if (label > 0.0f) {
                pos_cnt = 1.0f;
                const float aw = a.z - a.x, ah = a.w - a.y;
                const float acx = a.x + 0.5f * aw, acy = a.y + 0.5f * ah;
                const float gw = fmaxf(s_ann[bi*5+2] - s_ann[bi*5+0], 1.0f);
                const float gh = fmaxf(s_ann[bi*5+3] - s_ann[bi*5+1], 1.0f);
                const float gcx = s_ann[bi*5+0] + 0.5f * gw;
                const float gcy = s_ann[bi*5+1] + 0.5f * gh;
                const float tx = (gcx - acx) / aw * 10.0f;
                const float ty = (gcy - acy) / ah * 10.0f;
                const float tw = __logf(gw / aw) * 5.0f;
                const float th = __logf(gh / ah) * 5.0f;
                const float4 r = *(const float4*)(reg_heads + ((size_t)b * N + n) * 4);
                const float dx[4] = { fabsf(r.x - tx), fabsf(r.y - ty),
                                      fabsf(r.z - tw), fabsf(r.w - th) };
                #pragma unroll
                for (int j = 0; j < 4; ++j) {
                    const float x = dx[j];
                    reg_acc += (x < (1.0f / 9.0f)) ? 4.5f * x * x
                                                   : x - (1.0f / 18.0f);
                }
            }
        }
    }
    s_lab[t] = label;
    const int anyValid = __syncthreads_or(label >= 0.0f ? 1 : 0);

    // ---- phase 2: focal loss, software-pipelined depth-PF conditional loads ----
    // Loads stay exec-mask-conditional (lab<0 lanes issue nothing): the ~35%
    // byte skip is the ONE lever that beats the drain-contention window.
    float cls_acc = 0.0f;
    if (anyValid) {
        const float* cls_base = cls_heads + ((size_t)b * N + n0) * 80;
        int ap = t / 20, c4p = t - ap * 20;   // prefetch iterator
        int c4c = c4p;                        // process iterator (chunk only)
        float labb[PF];
        fvec4 pb[PF];
        #pragma unroll
        for (int k = 0; k < PF; ++k) {
            const float lab = s_lab[ap];
            fvec4 v = {0.5f, 0.5f, 0.5f, 0.5f};
            if (lab >= 0.0f) v = *(const fvec4*)(cls_base + 4 * t + 1024 * k);
            labb[k] = lab; pb[k] = v;
            ap += 12; c4p += 16; if (c4p >= 20) { c4p -= 20; ++ap; }
        }
        #pragma unroll
        for (int k = 0; k < 20; ++k) {
            const float lab = labb[k % PF];
            const fvec4 v   = pb[k % PF];
            if (k + PF < 20) {                 // refill slot with iter k+PF
                const float labn = s_lab[ap];
                fvec4 vn = {0.5f, 0.5f, 0.5f, 0.5f};
                if (labn >= 0.0f)
                    vn = *(const fvec4*)(cls_base + 4 * t + 1024 * (k + PF));
                labb[k % PF] = labn; pb[k % PF] = vn;
                ap += 12; c4p += 16; if (c4p >= 20) { c4p -= 20; ++ap; }
            }
            const float mask = (lab >= 0.0f) ? 1.0f : 0.0f;
            const float pv[4] = { v.x, v.y, v.z, v.w };
            const float cb = (float)(c4c * 4 + 1);
            float local = 0.0f;
            #pragma unroll
            for (int j = 0; j < 4; ++j) {
                const float p = fminf(fmaxf(pv[j], 1.0e-4f), 1.0f - 1.0e-4f);
                const bool  is_pos = (lab == cb + (float)j);
                const float pt     = is_pos ? p : 1.0f - p;
                const float alpha  = is_pos ? 0.25f : 0.75f;
                const float om     = 1.0f - pt;
                local += alpha * om * om * (-__logf(pt));
            }
            cls_acc += mask * local;
            c4c += 16; if (c4c >= 20) c4c -= 20;
        }
    }

    // ---- block reduction ----
    const int lane = t & 63, wid = t >> 6;
    #pragma unroll
    for (int off = 32; off > 0; off >>= 1) {
        cls_acc += __shfl_down(cls_acc, off, 64);
        reg_acc += __shfl_down(reg_acc, off, 64);
        pos_cnt += __shfl_down(pos_cnt, off, 64);
    }
    if (lane == 0) {
        s_red[wid]     = cls_acc;
        s_red[4 + wid] = reg_acc;
        s_red[8 + wid] = pos_cnt;
    }
    __syncthreads();
    if (t == 0) {
        const float c = s_red[0] + s_red[1] + s_red[2]  + s_red[3];
        const float r = s_red[4] + s_red[5] + s_red[6]  + s_red[7];
        const float p = s_red[8] + s_red[9] + s_red[10] + s_red[11];
        if (c != 0.0f) atomicAdd(&ws[b], c);
        if (r != 0.0f) atomicAdd(&ws[B + b], r);
        if (p != 0.0f) atomicAdd(&ws[2 * B + b], p);
    }
}

__global__ void retina_final(const float* __restrict__ ws,
                             float* __restrict__ out, int B)
{
    if (threadIdx.x == 0 && blockIdx.x == 0) {
        float cl = 0.0f, rl = 0.0f, nv = 0.0f;
        for (int b = 0; b < B; ++b) {
            const float pos = ws[2 * B + b];
            if (pos > 0.0f) {
                cl += ws[b]     / fmaxf(pos, 1.0f);
                rl += ws[B + b] / fmaxf(4.0f * pos, 1.0f);
                nv += 1.0f;
            }
        }
        const float n = fmaxf(nv, 1.0f);
        out[0] = cl / n;
        out[1] = rl / n;
    }
}

extern "C" void kernel_launch(void* const* d_in, const int* in_sizes, int n_in,
                              void* d_out, int out_size, void* d_ws, size_t ws_size,
                              hipStream_t stream) {
    const float* cls = (const float*)d_in[0];
    const float* reg = (const float*)d_in[1];
    const float* anc = (const float*)d_in[2];
    const float* ann = (const float*)d_in[3];

    const int B = 4;
    const int N = in_sizes[1] / (4 * B);      // 76725
    const int M = in_sizes[3] / (5 * B);      // 16
    float* ws = (float*)d_ws;

    (void)hipMemsetAsync(d_ws, 0, 12 * sizeof(float), stream);

    dim3 grid((N + 255) / 256, B);
    retina_main<<<grid, 256, 0, stream>>>(cls, reg, anc, ann, ws, N, M, B);
    retina_final<<<1, 64, 0, stream>>>(ws, (float*)d_out, B);
}